// Round 4
// baseline (625.077 us; speedup 1.0000x reference)
//
#include <hip/hip_runtime.h>
#include <cstdint>
#include <cstddef>

#define E_ 8
#define D_ 768
#define F_ 3072
#define N_ 16384
#define CAP_ 2560   // int(1.25 * 16384 / 8)
#define NCHUNK_ (N_ / 256)   // 64

typedef __attribute__((ext_vector_type(8))) short bf16x8;
typedef __attribute__((ext_vector_type(4))) float f32x4;

__device__ __forceinline__ unsigned short f2bf(float f) {
  unsigned u = __float_as_uint(f);
  u += 0x7fffu + ((u >> 16) & 1u);   // round-to-nearest-even
  return (unsigned short)(u >> 16);
}

__device__ __forceinline__ void gload16(const void* g, void* l) {
  __builtin_amdgcn_global_load_lds(
      (const __attribute__((address_space(1))) void*)g,
      (__attribute__((address_space(3))) void*)l, 16, 0, 0);
}

// ---------------- transpose + cast weights: src [E][R][C] fp32 -> dst [E][C][R] bf16 ----------------
__global__ void tcast_kernel(const float* __restrict__ src, unsigned short* __restrict__ dst,
                             int R, int C) {
  __shared__ float tile[64][65];
  int e = blockIdx.z;
  const float* s = src + (size_t)e * R * C;
  unsigned short* d = dst + (size_t)e * R * C;
  int c0 = blockIdx.x * 64, r0 = blockIdx.y * 64;
  int tx = threadIdx.x, ty = threadIdx.y;
  #pragma unroll
  for (int rr = ty; rr < 64; rr += 8) {
    tile[rr][tx]      = s[(size_t)(r0 + rr) * C + c0 + tx];
    tile[rr][tx + 32] = s[(size_t)(r0 + rr) * C + c0 + tx + 32];
  }
  __syncthreads();
  // widened stores: each thread writes ushort4 (8 B); 16 lanes -> 128 B contiguous.
  int rr = 4 * (tx & 15);
  int ccb = (tx >> 4) + 2 * ty;
  #pragma unroll
  for (int m = 0; m < 4; ++m) {
    int cc = ccb + 16 * m;
    ushort4 o;
    o.x = f2bf(tile[rr + 0][cc]);   // LDS stride 4*65 words between lanes -> 2-way, free
    o.y = f2bf(tile[rr + 1][cc]);
    o.z = f2bf(tile[rr + 2][cc]);
    o.w = f2bf(tile[rr + 3][cc]);
    *(ushort4*)&d[(size_t)(c0 + cc) * R + r0 + rr] = o;
  }
}

// ---------------- router (fused x->bf16 cast) ----------------
__global__ __launch_bounds__(256) void router_kernel(
    const float* __restrict__ x, const float* __restrict__ sw, const float* __restrict__ sb,
    int* __restrict__ route, float* __restrict__ prob,
    unsigned short* __restrict__ xb) {
  __shared__ float wl[E_ * D_];
  int tid = threadIdx.x;
  #pragma unroll
  for (int ee = 0; ee < E_; ++ee)
    for (int dd = tid; dd < D_; dd += 256)
      wl[ee * D_ + dd] = sw[dd * E_ + ee];
  __syncthreads();
  int wave = tid >> 6, lane = tid & 63;
  int tbase = blockIdx.x * 16 + wave * 4;
  #pragma unroll
  for (int tt = 0; tt < 4; ++tt) {
    int t = tbase + tt;
    const float* xp = x + (size_t)t * D_;
    unsigned short* xbp = xb + (size_t)t * D_;
    float acc[E_];
    #pragma unroll
    for (int e = 0; e < E_; ++e) acc[e] = 0.f;
    #pragma unroll
    for (int r = 0; r < D_ / 64; ++r) {
      int dd = r * 64 + lane;
      float xv = xp[dd];
      xbp[dd] = f2bf(xv);
      #pragma unroll
      for (int e = 0; e < E_; ++e) acc[e] += xv * wl[e * D_ + dd];
    }
    #pragma unroll
    for (int e = 0; e < E_; ++e) {
      #pragma unroll
      for (int o = 32; o > 0; o >>= 1) acc[e] += __shfl_xor(acc[e], o);
    }
    if (lane == 0) {
      float mx = -1e30f; int arg = 0;
      #pragma unroll
      for (int e = 0; e < E_; ++e) {
        float l = acc[e] + sb[e];
        acc[e] = l;
        if (l > mx) { mx = l; arg = e; }
      }
      float s = 0.f;
      #pragma unroll
      for (int e = 0; e < E_; ++e) s += expf(acc[e] - mx);
      route[t] = arg;
      prob[t] = 1.f / s;
    }
  }
}

// ---------------- per-chunk histogram ----------------
__global__ void hist_kernel(const int* __restrict__ route, int* __restrict__ chunk_hist) {
  __shared__ int h[E_];
  int tid = threadIdx.x;
  if (tid < E_) h[tid] = 0;
  __syncthreads();
  atomicAdd(&h[route[blockIdx.x * 256 + tid]], 1);
  __syncthreads();
  if (tid < E_) chunk_hist[blockIdx.x * E_ + tid] = h[tid];
}

// ---------------- exclusive scan over chunks per expert ----------------
__global__ void scan_kernel(const int* __restrict__ chunk_hist, int* __restrict__ chunk_off,
                            int* __restrict__ counts) {
  __shared__ int h[NCHUNK_ * E_];
  int tid = threadIdx.x;
  h[tid] = chunk_hist[tid];
  __syncthreads();
  if (tid < E_) {
    int run = 0;
    for (int c = 0; c < NCHUNK_; ++c) {
      chunk_off[c * E_ + tid] = run;
      run += h[c * E_ + tid];
    }
    counts[tid] = run;
  }
}

// ---------------- slot assignment ----------------
__global__ void assign_kernel(const int* __restrict__ route, const float* __restrict__ prob,
                              const int* __restrict__ counts, const int* __restrict__ chunk_off,
                              int* __restrict__ tok_list, int* __restrict__ slot) {
  __shared__ int rt[256];
  int tid = threadIdx.x;
  int i = blockIdx.x * 256 + tid;
  int e = route[i];
  rt[tid] = e;
  __syncthreads();
  int r = 0;
  for (int j = 0; j < tid; ++j) r += (rt[j] == e) ? 1 : 0;
  int c = counts[e];
  int s; bool keep;
  if (c <= CAP_) {
    s = chunk_off[blockIdx.x * E_ + e] + r;
    keep = true;
  } else {
    float p = prob[i];
    int rr = 0;
    for (int j = 0; j < N_; ++j) {
      if (route[j] == e) {
        float pj = prob[j];
        rr += (pj > p || (pj == p && j < i)) ? 1 : 0;
      }
    }
    s = rr; keep = (rr < CAP_);
  }
  if (keep) tok_list[e * CAP_ + s] = i;
  slot[i] = keep ? s : -1;
}

// =====================================================================================
// GEMMs: r0's proven 128x128 single-buffer 2-barrier structure, upgraded with
//   - BK=64 (half the barrier/drain events, 8 dwordx4 loads in flight per drain)
//   - T2 chunk-swizzle: LDS slot (row, c) holds global chunk c ^ (row&7); applied by
//     permuting the per-lane GLOBAL source chunk (gload_lds dest stays linear) and
//     XOR-ing the fragment-read chunk. Verified zero-conflict in r1-r3.
//   - T1 XCD-chunked grid swizzle: one expert per XCD (FETCH 216->73 MB proven).
// LDS: A [128 rows][128 B] @0, B @16384 bytes. 32 KiB total -> ~5 blocks/CU.
// Staging: pass ar covers rows ar*32 + w*8 + (lane>>3); dest = ar*4096 + w*1024
// (+lane*16 implicit). Fragment read byte = row*128 + ((kk*4+q)^(fr&7))*16, where
// the kk=1 flip is ^64 on the byte address.
// =====================================================================================

#define STAGE8(ko)                                            \
  gload16(pA0 + (ko), smw + 0 * 4096 + w * 1024);             \
  gload16(pA1 + (ko), smw + 1 * 4096 + w * 1024);             \
  gload16(pA2 + (ko), smw + 2 * 4096 + w * 1024);             \
  gload16(pA3 + (ko), smw + 3 * 4096 + w * 1024);             \
  gload16(pB0 + (ko), smw + 16384 + 0 * 4096 + w * 1024);     \
  gload16(pB1 + (ko), smw + 16384 + 1 * 4096 + w * 1024);     \
  gload16(pB2 + (ko), smw + 16384 + 2 * 4096 + w * 1024);     \
  gload16(pB3 + (ko), smw + 16384 + 3 * 4096 + w * 1024);

#define MFMA16(A_, B_)                                                            \
  _Pragma("unroll") for (int i = 0; i < 4; ++i)                                   \
  _Pragma("unroll") for (int j = 0; j < 4; ++j)                                   \
    acc[i][j] = __builtin_amdgcn_mfma_f32_16x16x32_bf16(A_[i], B_[j], acc[i][j], 0, 0, 0);

// ---------------- GEMM1: h[e][m][f] = gelu( x[tok] @ w1[e] + b1[e] ) ----------------
__global__ __launch_bounds__(256) void gemm1_kernel(
    const unsigned short* __restrict__ xb, const unsigned short* __restrict__ w1t,
    const float* __restrict__ b1, const int* __restrict__ tok_list,
    const int* __restrict__ counts, unsigned short* __restrict__ hb) {
  // T1: 3840 blocks, 480 per expert -> XCD k owns expert k
  int flat = blockIdx.x + 20 * (blockIdx.y + 24 * blockIdx.z);
  int work = (flat & 7) * 480 + (flat >> 3);
  int e = work / 480;
  int rem = work % 480;
  int xm = rem % 20, yn = rem / 20;
  int Me = counts[e] < CAP_ ? counts[e] : CAP_;
  int m0 = xm * 128;
  if (m0 >= Me) return;
  int n0 = yn * 128;
  __shared__ unsigned short sm[16384];   // A 16 KiB | B 16 KiB
  char* smw = (char*)sm;
  const char* smc = (const char*)sm;
  int tid = threadIdx.x, lane = tid & 63, w = tid >> 6;
  int l8 = lane >> 3;
  int sc = (lane & 7) ^ l8;              // pre-swizzled source chunk
  int rbase = w * 8 + l8;                // row within 32-row pass
  // A sources: gathered token rows (clamped; rows >= Me discarded at store guard)
  int r0_ = m0 + rbase;       if (r0_ > Me - 1) r0_ = Me - 1;
  int r1_ = m0 + 32 + rbase;  if (r1_ > Me - 1) r1_ = Me - 1;
  int r2_ = m0 + 64 + rbase;  if (r2_ > Me - 1) r2_ = Me - 1;
  int r3_ = m0 + 96 + rbase;  if (r3_ > Me - 1) r3_ = Me - 1;
  const unsigned short* pA0 = xb + (size_t)tok_list[e * CAP_ + r0_] * D_ + sc * 8;
  const unsigned short* pA1 = xb + (size_t)tok_list[e * CAP_ + r1_] * D_ + sc * 8;
  const unsigned short* pA2 = xb + (size_t)tok_list[e * CAP_ + r2_] * D_ + sc * 8;
  const unsigned short* pA3 = xb + (size_t)tok_list[e * CAP_ + r3_] * D_ + sc * 8;
  const unsigned short* pB0 = w1t + ((size_t)e * F_ + n0 + rbase) * D_ + sc * 8;
  const unsigned short* pB1 = w1t + ((size_t)e * F_ + n0 + 32 + rbase) * D_ + sc * 8;
  const unsigned short* pB2 = w1t + ((size_t)e * F_ + n0 + 64 + rbase) * D_ + sc * 8;
  const unsigned short* pB3 = w1t + ((size_t)e * F_ + n0 + 96 + rbase) * D_ + sc * 8;
  // fragment geometry
  int fr = lane & 15, q = lane >> 4, fr7 = fr & 7;
  int wm = (w >> 1) * 64, wn = (w & 1) * 64;
  unsigned aoff = (unsigned)((wm + fr) * 128 + ((q ^ fr7) * 16));
  unsigned boff = (unsigned)(16384 + (wn + fr) * 128 + ((q ^ fr7) * 16));
  f32x4 acc[4][4] = {};
  for (int k0 = 0; k0 < D_; k0 += 64) {
    __syncthreads();
    STAGE8((size_t)k0)
    __syncthreads();
    bf16x8 a[4], b[4];
    #pragma unroll
    for (int i = 0; i < 4; ++i) a[i] = *(const bf16x8*)(smc + aoff + i * 2048);
    #pragma unroll
    for (int j = 0; j < 4; ++j) b[j] = *(const bf16x8*)(smc + boff + j * 2048);
    MFMA16(a, b)
    #pragma unroll
    for (int i = 0; i < 4; ++i) a[i] = *(const bf16x8*)(smc + (aoff ^ 64u) + i * 2048);
    #pragma unroll
    for (int j = 0; j < 4; ++j) b[j] = *(const bf16x8*)(smc + (boff ^ 64u) + j * 2048);
    MFMA16(a, b)
  }
  int q4 = q * 4;
  #pragma unroll
  for (int i = 0; i < 4; ++i) {
    #pragma unroll
    for (int j = 0; j < 4; ++j) {
      int col = n0 + wn + j * 16 + fr;
      float bias = b1[e * F_ + col];
      #pragma unroll
      for (int r = 0; r < 4; ++r) {
        int row = m0 + wm + i * 16 + q4 + r;
        if (row < Me) {
          float v = acc[i][j][r] + bias;
          v = 0.5f * v * (1.f + erff(v * 0.70710678118654752f));   // exact GELU
          hb[((size_t)e * CAP_ + row) * F_ + col] = f2bf(v);
        }
      }
    }
  }
}

// ---------------- GEMM2: out[tok] = (h[e] @ w2[e] + b2[e]) * prob[tok] ----------------
__global__ __launch_bounds__(256) void gemm2_kernel(
    const unsigned short* __restrict__ hb, const unsigned short* __restrict__ w2t,
    const float* __restrict__ b2, const int* __restrict__ tok_list,
    const int* __restrict__ counts, const float* __restrict__ prob,
    float* __restrict__ out) {
  // T1: 960 blocks, 120 per expert -> XCD k owns expert k
  int flat = blockIdx.x + 20 * (blockIdx.y + 6 * blockIdx.z);
  int work = (flat & 7) * 120 + (flat >> 3);
  int e = work / 120;
  int rem = work % 120;
  int xm = rem % 20, yn = rem / 20;
  int Me = counts[e] < CAP_ ? counts[e] : CAP_;
  int m0 = xm * 128;
  if (m0 >= Me) return;
  int n0 = yn * 128;
  __shared__ unsigned short sm[16384];
  char* smw = (char*)sm;
  const char* smc = (const char*)sm;
  int tid = threadIdx.x, lane = tid & 63, w = tid >> 6;
  int l8 = lane >> 3;
  int sc = (lane & 7) ^ l8;
  int rbase = w * 8 + l8;
  // A: dense hb rows (rows >= Me hold finite poison, discarded by store guard)
  const unsigned short* pA0 = hb + ((size_t)e * CAP_ + m0 + rbase) * F_ + sc * 8;
  const unsigned short* pA1 = hb + ((size_t)e * CAP_ + m0 + 32 + rbase) * F_ + sc * 8;
  const unsigned short* pA2 = hb + ((size_t)e * CAP_ + m0 + 64 + rbase) * F_ + sc * 8;
  const unsigned short* pA3 = hb + ((size_t)e * CAP_ + m0 + 96 + rbase) * F_ + sc * 8;
  const unsigned short* pB0 = w2t + ((size_t)e * D_ + n0 + rbase) * F_ + sc * 8;
  const unsigned short* pB1 = w2t + ((size_t)e * D_ + n0 + 32 + rbase) * F_ + sc * 8;
  const unsigned short* pB2 = w2t + ((size_t)e * D_ + n0 + 64 + rbase) * F_ + sc * 8;
  const unsigned short* pB3 = w2t + ((size_t)e * D_ + n0 + 96 + rbase) * F_ + sc * 8;
  int fr = lane & 15, q = lane >> 4, fr7 = fr & 7;
  int wm = (w >> 1) * 64, wn = (w & 1) * 64;
  unsigned aoff = (unsigned)((wm + fr) * 128 + ((q ^ fr7) * 16));
  unsigned boff = (unsigned)(16384 + (wn + fr) * 128 + ((q ^ fr7) * 16));
  f32x4 acc[4][4] = {};
  for (int k0 = 0; k0 < F_; k0 += 64) {
    __syncthreads();
    STAGE8((size_t)k0)
    __syncthreads();
    bf16x8 a[4], b[4];
    #pragma unroll
    for (int i = 0; i < 4; ++i) a[i] = *(const bf16x8*)(smc + aoff + i * 2048);
    #pragma unroll
    for (int j = 0; j < 4; ++j) b[j] = *(const bf16x8*)(smc + boff + j * 2048);
    MFMA16(a, b)
    #pragma unroll
    for (int i = 0; i < 4; ++i) a[i] = *(const bf16x8*)(smc + (aoff ^ 64u) + i * 2048);
    #pragma unroll
    for (int j = 0; j < 4; ++j) b[j] = *(const bf16x8*)(smc + (boff ^ 64u) + j * 2048);
    MFMA16(a, b)
  }
  int q4 = q * 4;
  #pragma unroll
  for (int i = 0; i < 4; ++i) {
    #pragma unroll
    for (int r = 0; r < 4; ++r) {
      int row = m0 + wm + i * 16 + q4 + r;
      if (row < Me) {
        int tok = tok_list[e * CAP_ + row];
        float pm = prob[tok];
        #pragma unroll
        for (int j = 0; j < 4; ++j) {
          int col = n0 + wn + j * 16 + fr;
          float v = (acc[i][j][r] + b2[e * D_ + col]) * pm;
          out[(size_t)tok * D_ + col] = v;
        }
      }
    }
  }
}

// ---------------- passthrough for dropped tokens ----------------
__global__ void passthrough_kernel(const float* __restrict__ x, const float* __restrict__ prob,
                                   const int* __restrict__ slot, float* __restrict__ out) {
  int t = blockIdx.x;
  if (slot[t] >= 0) return;
  float p = prob[t];
  for (int d = threadIdx.x; d < D_; d += 256)
    out[(size_t)t * D_ + d] = x[(size_t)t * D_ + d] * p;
}

extern "C" void kernel_launch(void* const* d_in, const int* in_sizes, int n_in,
                              void* d_out, int out_size, void* d_ws, size_t ws_size,
                              hipStream_t stream) {
  const float* x  = (const float*)d_in[0];
  const float* sw = (const float*)d_in[1];
  const float* sb = (const float*)d_in[2];
  const float* w1 = (const float*)d_in[3];
  const float* b1 = (const float*)d_in[4];
  const float* w2 = (const float*)d_in[5];
  const float* b2 = (const float*)d_in[6];
  float* out = (float*)d_out;
  (void)in_sizes; (void)n_in; (void)out_size; (void)ws_size;

  char* ws = (char*)d_ws;
  size_t off = 0;
  auto alloc = [&](size_t bytes) {
    char* p = ws + off;
    off = (off + bytes + 255) & ~(size_t)255;
    return p;
  };
  int* counts     = (int*)alloc(32 * sizeof(int));
  int* chunk_hist = (int*)alloc((size_t)NCHUNK_ * E_ * sizeof(int));
  int* chunk_off  = (int*)alloc((size_t)NCHUNK_ * E_ * sizeof(int));
  int* tok_list   = (int*)alloc((size_t)E_ * CAP_ * sizeof(int));
  int* route      = (int*)alloc((size_t)N_ * 4);
  float* prob     = (float*)alloc((size_t)N_ * 4);
  int* slot       = (int*)alloc((size_t)N_ * 4);
  unsigned short* xb  = (unsigned short*)alloc((size_t)N_ * D_ * 2);
  unsigned short* w1t = (unsigned short*)alloc((size_t)E_ * D_ * F_ * 2);
  unsigned short* w2t = (unsigned short*)alloc((size_t)E_ * D_ * F_ * 2);
  unsigned short* hb  = (unsigned short*)alloc((size_t)E_ * CAP_ * F_ * 2);

  dim3 tb(32, 8);
  tcast_kernel<<<dim3(F_ / 64, D_ / 64, E_), tb, 0, stream>>>(w1, w1t, D_, F_);
  tcast_kernel<<<dim3(D_ / 64, F_ / 64, E_), tb, 0, stream>>>(w2, w2t, F_, D_);
  router_kernel<<<N_ / 16, 256, 0, stream>>>(x, sw, sb, route, prob, xb);
  hist_kernel<<<NCHUNK_, 256, 0, stream>>>(route, chunk_hist);
  scan_kernel<<<1, NCHUNK_ * E_, 0, stream>>>(chunk_hist, chunk_off, counts);
  assign_kernel<<<NCHUNK_, 256, 0, stream>>>(route, prob, counts, chunk_off, tok_list, slot);
  gemm1_kernel<<<dim3(20, 24, 8), 256, 0, stream>>>(xb, w1t, b1, tok_list, counts, hb);
  gemm2_kernel<<<dim3(20, 6, 8), 256, 0, stream>>>(hb, w2t, b2, tok_list, counts, prob, out);
  passthrough_kernel<<<N_, 256, 0, stream>>>(x, prob, slot, out);
}

// Round 5
// 539.020 us; speedup vs baseline: 1.1597x; 1.1597x over previous
//
#include <hip/hip_runtime.h>
#include <cstdint>
#include <cstddef>

#define E_ 8
#define D_ 768
#define F_ 3072
#define N_ 16384
#define CAP_ 2560   // int(1.25 * 16384 / 8)
#define NCHUNK_ (N_ / 256)   // 64

typedef __attribute__((ext_vector_type(8))) short bf16x8;
typedef __attribute__((ext_vector_type(4))) float f32x4;

__device__ __forceinline__ unsigned short f2bf(float f) {
  unsigned u = __float_as_uint(f);
  u += 0x7fffu + ((u >> 16) & 1u);   // round-to-nearest-even
  return (unsigned short)(u >> 16);
}

__device__ __forceinline__ void gload16(const void* g, void* l) {
  __builtin_amdgcn_global_load_lds(
      (const __attribute__((address_space(1))) void*)g,
      (__attribute__((address_space(3))) void*)l, 16, 0, 0);
}

// ---------------- transpose + cast weights: src [E][R][C] fp32 -> dst [E][C][R] bf16 ----------------
__global__ void tcast_kernel(const float* __restrict__ src, unsigned short* __restrict__ dst,
                             int R, int C) {
  __shared__ float tile[64][65];
  int e = blockIdx.z;
  const float* s = src + (size_t)e * R * C;
  unsigned short* d = dst + (size_t)e * R * C;
  int c0 = blockIdx.x * 64, r0 = blockIdx.y * 64;
  int tx = threadIdx.x, ty = threadIdx.y;
  #pragma unroll
  for (int rr = ty; rr < 64; rr += 8) {
    tile[rr][tx]      = s[(size_t)(r0 + rr) * C + c0 + tx];
    tile[rr][tx + 32] = s[(size_t)(r0 + rr) * C + c0 + tx + 32];
  }
  __syncthreads();
  // widened stores: each thread writes ushort4 (8 B); 16 lanes -> 128 B contiguous.
  int rr = 4 * (tx & 15);
  int ccb = (tx >> 4) + 2 * ty;
  #pragma unroll
  for (int m = 0; m < 4; ++m) {
    int cc = ccb + 16 * m;
    ushort4 o;
    o.x = f2bf(tile[rr + 0][cc]);
    o.y = f2bf(tile[rr + 1][cc]);
    o.z = f2bf(tile[rr + 2][cc]);
    o.w = f2bf(tile[rr + 3][cc]);
    *(ushort4*)&d[(size_t)(c0 + cc) * R + r0 + rr] = o;
  }
}

// ---------------- router (fused x->bf16 cast) ----------------
__global__ __launch_bounds__(256) void router_kernel(
    const float* __restrict__ x, const float* __restrict__ sw, const float* __restrict__ sb,
    int* __restrict__ route, float* __restrict__ prob,
    unsigned short* __restrict__ xb) {
  __shared__ float wl[E_ * D_];
  int tid = threadIdx.x;
  #pragma unroll
  for (int ee = 0; ee < E_; ++ee)
    for (int dd = tid; dd < D_; dd += 256)
      wl[ee * D_ + dd] = sw[dd * E_ + ee];
  __syncthreads();
  int wave = tid >> 6, lane = tid & 63;
  int tbase = blockIdx.x * 16 + wave * 4;
  #pragma unroll
  for (int tt = 0; tt < 4; ++tt) {
    int t = tbase + tt;
    const float* xp = x + (size_t)t * D_;
    unsigned short* xbp = xb + (size_t)t * D_;
    float acc[E_];
    #pragma unroll
    for (int e = 0; e < E_; ++e) acc[e] = 0.f;
    #pragma unroll
    for (int r = 0; r < D_ / 64; ++r) {
      int dd = r * 64 + lane;
      float xv = xp[dd];
      xbp[dd] = f2bf(xv);
      #pragma unroll
      for (int e = 0; e < E_; ++e) acc[e] += xv * wl[e * D_ + dd];
    }
    #pragma unroll
    for (int e = 0; e < E_; ++e) {
      #pragma unroll
      for (int o = 32; o > 0; o >>= 1) acc[e] += __shfl_xor(acc[e], o);
    }
    if (lane == 0) {
      float mx = -1e30f; int arg = 0;
      #pragma unroll
      for (int e = 0; e < E_; ++e) {
        float l = acc[e] + sb[e];
        acc[e] = l;
        if (l > mx) { mx = l; arg = e; }
      }
      float s = 0.f;
      #pragma unroll
      for (int e = 0; e < E_; ++e) s += expf(acc[e] - mx);
      route[t] = arg;
      prob[t] = 1.f / s;
    }
  }
}

// ---------------- per-chunk histogram ----------------
__global__ void hist_kernel(const int* __restrict__ route, int* __restrict__ chunk_hist) {
  __shared__ int h[E_];
  int tid = threadIdx.x;
  if (tid < E_) h[tid] = 0;
  __syncthreads();
  atomicAdd(&h[route[blockIdx.x * 256 + tid]], 1);
  __syncthreads();
  if (tid < E_) chunk_hist[blockIdx.x * E_ + tid] = h[tid];
}

// ---------------- exclusive scan over chunks per expert ----------------
__global__ void scan_kernel(const int* __restrict__ chunk_hist, int* __restrict__ chunk_off,
                            int* __restrict__ counts) {
  __shared__ int h[NCHUNK_ * E_];
  int tid = threadIdx.x;
  h[tid] = chunk_hist[tid];
  __syncthreads();
  if (tid < E_) {
    int run = 0;
    for (int c = 0; c < NCHUNK_; ++c) {
      chunk_off[c * E_ + tid] = run;
      run += h[c * E_ + tid];
    }
    counts[tid] = run;
  }
}

// ---------------- slot assignment ----------------
__global__ void assign_kernel(const int* __restrict__ route, const float* __restrict__ prob,
                              const int* __restrict__ counts, const int* __restrict__ chunk_off,
                              int* __restrict__ tok_list, int* __restrict__ slot) {
  __shared__ int rt[256];
  int tid = threadIdx.x;
  int i = blockIdx.x * 256 + tid;
  int e = route[i];
  rt[tid] = e;
  __syncthreads();
  int r = 0;
  for (int j = 0; j < tid; ++j) r += (rt[j] == e) ? 1 : 0;
  int c = counts[e];
  int s; bool keep;
  if (c <= CAP_) {
    s = chunk_off[blockIdx.x * E_ + e] + r;
    keep = true;
  } else {
    float p = prob[i];
    int rr = 0;
    for (int j = 0; j < N_; ++j) {
      if (route[j] == e) {
        float pj = prob[j];
        rr += (pj > p || (pj == p && j < i)) ? 1 : 0;
      }
    }
    s = rr; keep = (rr < CAP_);
  }
  if (keep) tok_list[e * CAP_ + s] = i;
  slot[i] = keep ? s : -1;
}

// ---------------- GEMM1: r0's proven 128x128 / BK=32 structure + conflict-lite swizzle.
// LDS rows are 64 B = 4 x 16 B chunks. Slot s at row r holds global chunk s ^ (r&3):
// applied via the per-lane GLOBAL source chunk (gload_lds dest stays linear) and an
// XOR on the fragment-read chunk. ds_read_b128 conflicts: 8-way -> 4-way. ----------------
__global__ __launch_bounds__(256) void gemm1_kernel(
    const unsigned short* __restrict__ xb, const unsigned short* __restrict__ w1t,
    const float* __restrict__ b1, const int* __restrict__ tok_list,
    const int* __restrict__ counts, unsigned short* __restrict__ hb) {
  int e = blockIdx.z;
  int Me = counts[e] < CAP_ ? counts[e] : CAP_;
  int m0 = blockIdx.x * 128;
  if (m0 >= Me) return;
  int n0 = blockIdx.y * 128;
  __shared__ unsigned short At[128 * 32];
  __shared__ unsigned short Bt[128 * 32];
  int tid = threadIdx.x, lane = tid & 63, wave = tid >> 6;
  int rA0 = (wave * 2 + 0) * 16 + (lane >> 2);
  int rA1 = (wave * 2 + 1) * 16 + (lane >> 2);
  // swizzled source chunk: slot (lane&3) at row (lane>>2) gets global chunk (lane&3)^(row&3)
  int cb = (((lane & 3) ^ ((lane >> 2) & 3))) * 16;   // byte offset within 64B row
  int mr0 = m0 + rA0; if (mr0 > Me - 1) mr0 = Me - 1;
  int mr1 = m0 + rA1; if (mr1 > Me - 1) mr1 = Me - 1;
  int tok0 = tok_list[e * CAP_ + mr0];
  int tok1 = tok_list[e * CAP_ + mr1];
  const char* gA0 = (const char*)(xb + (size_t)tok0 * D_) + cb;
  const char* gA1 = (const char*)(xb + (size_t)tok1 * D_) + cb;
  const char* gB0 = (const char*)(w1t + ((size_t)e * F_ + n0 + rA0) * D_) + cb;
  const char* gB1 = (const char*)(w1t + ((size_t)e * F_ + n0 + rA1) * D_) + cb;
  unsigned short* lA0 = At + (wave * 2 + 0) * 512;
  unsigned short* lA1 = At + (wave * 2 + 1) * 512;
  unsigned short* lB0 = Bt + (wave * 2 + 0) * 512;
  unsigned short* lB1 = Bt + (wave * 2 + 1) * 512;
  f32x4 acc[4][4] = {};
  int wm = (wave >> 1) * 64, wn = (wave & 1) * 64;
  int fr = lane & 15;
  int fk = (((lane >> 4) ^ (lane & 3))) * 8;   // read chunk q ^ (row&3), row&3 == fr&3 == lane&3
  for (int k0 = 0; k0 < D_; k0 += 32) {
    __syncthreads();
    gload16(gA0 + (size_t)2 * k0, lA0);
    gload16(gA1 + (size_t)2 * k0, lA1);
    gload16(gB0 + (size_t)2 * k0, lB0);
    gload16(gB1 + (size_t)2 * k0, lB1);
    __syncthreads();
    bf16x8 a[4], b[4];
    #pragma unroll
    for (int i = 0; i < 4; ++i)
      a[i] = *(const bf16x8*)(At + (wm + i * 16 + fr) * 32 + fk);
    #pragma unroll
    for (int j = 0; j < 4; ++j)
      b[j] = *(const bf16x8*)(Bt + (wn + j * 16 + fr) * 32 + fk);
    #pragma unroll
    for (int i = 0; i < 4; ++i)
      #pragma unroll
      for (int j = 0; j < 4; ++j)
        acc[i][j] = __builtin_amdgcn_mfma_f32_16x16x32_bf16(a[i], b[j], acc[i][j], 0, 0, 0);
  }
  int q4 = (lane >> 4) * 4;
  #pragma unroll
  for (int i = 0; i < 4; ++i) {
    #pragma unroll
    for (int j = 0; j < 4; ++j) {
      int col = n0 + wn + j * 16 + (lane & 15);
      float bias = b1[e * F_ + col];
      #pragma unroll
      for (int r = 0; r < 4; ++r) {
        int row = m0 + wm + i * 16 + q4 + r;
        if (row < Me) {
          float v = acc[i][j][r] + bias;
          v = 0.5f * v * (1.f + erff(v * 0.70710678118654752f));   // exact GELU
          hb[((size_t)e * CAP_ + row) * F_ + col] = f2bf(v);
        }
      }
    }
  }
}

// ---------------- GEMM2: r1's 256x256 / BK=64 2-phase structure (proven best for K=3072).
// T2 chunk-swizzle (128B rows, 8 chunks): source chunk (lane&7)^(lane>>3), read chunk
// (kh*4+q)^(fr&7). Issue-early staging, one __syncthreads() drain per K-tile. ----------------
__global__ __launch_bounds__(512, 2) void gemm2_kernel(
    const unsigned short* __restrict__ hb, const unsigned short* __restrict__ w2t,
    const float* __restrict__ b2, const int* __restrict__ tok_list,
    const int* __restrict__ counts, const float* __restrict__ prob,
    float* __restrict__ out) {
  int e = blockIdx.z;
  int Me = counts[e] < CAP_ ? counts[e] : CAP_;
  int m0 = blockIdx.x * 256;
  if (m0 >= Me) return;
  int n0 = blockIdx.y * 256;
  __shared__ unsigned short sm[65536];
  int tid = threadIdx.x, lane = tid & 63, w = tid >> 6;
  int srow = w * 8 + (lane >> 3);
  int schunk = (lane & 7) ^ (lane >> 3);
  unsigned dstA = (unsigned)(w * 512);
  // A: dense hb rows (rows >= Me hold finite poison, discarded by store guard)
  const char* sA[4];
  #pragma unroll
  for (int ar = 0; ar < 4; ++ar)
    sA[ar] = (const char*)(hb + ((size_t)e * CAP_ + m0 + ar * 64 + srow) * F_) + schunk * 16;
  const char* sB = (const char*)(w2t + ((size_t)e * D_ + n0 + srow) * F_) + schunk * 16;
  const size_t BR = (size_t)64 * F_ * 2;
  int fr = lane & 15, q = lane >> 4;
  int wm = (w >> 2) * 128, wn = (w & 3) * 64;
  f32x4 acc[8][4] = {};

  #pragma unroll
  for (int ar = 0; ar < 4; ++ar) {
    gload16(sA[ar], sm + ar * 4096 + dstA);
    gload16(sB + ar * BR, sm + 16384 + ar * 4096 + dstA);
  }
  __syncthreads();

  const int NT = F_ / 64;   // 48
  for (int kt = 0; kt < NT; ++kt) {
    int cb = kt & 1;
    if (kt + 1 < NT) {
      int ob = cb ^ 1;
      size_t ko = (size_t)(kt + 1) * 128;
      #pragma unroll
      for (int ar = 0; ar < 4; ++ar) {
        gload16(sA[ar] + ko, sm + ob * 32768 + ar * 4096 + dstA);
        gload16(sB + ar * BR + ko, sm + ob * 32768 + 16384 + ar * 4096 + dstA);
      }
    }
    const unsigned short* A  = sm + cb * 32768;
    const unsigned short* Bm = A + 16384;
    #pragma unroll
    for (int kh = 0; kh < 2; ++kh) {
      bf16x8 bfr[4];
      #pragma unroll
      for (int j = 0; j < 4; ++j) {
        int row = wn + j * 16 + fr;
        int pc = (kh * 4 + q) ^ (fr & 7);
        bfr[j] = *(const bf16x8*)(Bm + row * 64 + pc * 8);
      }
      __builtin_amdgcn_s_setprio(1);
      #pragma unroll
      for (int i = 0; i < 8; ++i) {
        int row = wm + i * 16 + fr;
        int pc = (kh * 4 + q) ^ (fr & 7);
        bf16x8 afr = *(const bf16x8*)(A + row * 64 + pc * 8);
        #pragma unroll
        for (int j = 0; j < 4; ++j)
          acc[i][j] = __builtin_amdgcn_mfma_f32_16x16x32_bf16(afr, bfr[j], acc[i][j], 0, 0, 0);
      }
      __builtin_amdgcn_s_setprio(0);
    }
    __syncthreads();
  }

  int q4 = q * 4;
  #pragma unroll
  for (int i = 0; i < 8; ++i) {
    #pragma unroll
    for (int r = 0; r < 4; ++r) {
      int row = m0 + wm + i * 16 + q4 + r;
      if (row < Me) {
        int tok = tok_list[e * CAP_ + row];
        float pm = prob[tok];
        #pragma unroll
        for (int j = 0; j < 4; ++j) {
          int col = n0 + wn + j * 16 + fr;
          float v = (acc[i][j][r] + b2[e * D_ + col]) * pm;
          out[(size_t)tok * D_ + col] = v;
        }
      }
    }
  }
}

// ---------------- passthrough for dropped tokens ----------------
__global__ void passthrough_kernel(const float* __restrict__ x, const float* __restrict__ prob,
                                   const int* __restrict__ slot, float* __restrict__ out) {
  int t = blockIdx.x;
  if (slot[t] >= 0) return;
  float p = prob[t];
  for (int d = threadIdx.x; d < D_; d += 256)
    out[(size_t)t * D_ + d] = x[(size_t)t * D_ + d] * p;
}

extern "C" void kernel_launch(void* const* d_in, const int* in_sizes, int n_in,
                              void* d_out, int out_size, void* d_ws, size_t ws_size,
                              hipStream_t stream) {
  const float* x  = (const float*)d_in[0];
  const float* sw = (const float*)d_in[1];
  const float* sb = (const float*)d_in[2];
  const float* w1 = (const float*)d_in[3];
  const float* b1 = (const float*)d_in[4];
  const float* w2 = (const float*)d_in[5];
  const float* b2 = (const float*)d_in[6];
  float* out = (float*)d_out;
  (void)in_sizes; (void)n_in; (void)out_size; (void)ws_size;

  char* ws = (char*)d_ws;
  size_t off = 0;
  auto alloc = [&](size_t bytes) {
    char* p = ws + off;
    off = (off + bytes + 255) & ~(size_t)255;
    return p;
  };
  int* counts     = (int*)alloc(32 * sizeof(int));
  int* chunk_hist = (int*)alloc((size_t)NCHUNK_ * E_ * sizeof(int));
  int* chunk_off  = (int*)alloc((size_t)NCHUNK_ * E_ * sizeof(int));
  int* tok_list   = (int*)alloc((size_t)E_ * CAP_ * sizeof(int));
  int* route      = (int*)alloc((size_t)N_ * 4);
  float* prob     = (float*)alloc((size_t)N_ * 4);
  int* slot       = (int*)alloc((size_t)N_ * 4);
  unsigned short* xb  = (unsigned short*)alloc((size_t)N_ * D_ * 2);
  unsigned short* w1t = (unsigned short*)alloc((size_t)E_ * D_ * F_ * 2);
  unsigned short* w2t = (unsigned short*)alloc((size_t)E_ * D_ * F_ * 2);
  unsigned short* hb  = (unsigned short*)alloc((size_t)E_ * CAP_ * F_ * 2);

  dim3 tb(32, 8);
  tcast_kernel<<<dim3(F_ / 64, D_ / 64, E_), tb, 0, stream>>>(w1, w1t, D_, F_);
  tcast_kernel<<<dim3(D_ / 64, F_ / 64, E_), tb, 0, stream>>>(w2, w2t, F_, D_);
  router_kernel<<<N_ / 16, 256, 0, stream>>>(x, sw, sb, route, prob, xb);
  hist_kernel<<<NCHUNK_, 256, 0, stream>>>(route, chunk_hist);
  scan_kernel<<<1, NCHUNK_ * E_, 0, stream>>>(chunk_hist, chunk_off, counts);
  assign_kernel<<<NCHUNK_, 256, 0, stream>>>(route, prob, counts, chunk_off, tok_list, slot);
  gemm1_kernel<<<dim3(CAP_ / 128, F_ / 128, E_), 256, 0, stream>>>(xb, w1t, b1, tok_list, counts, hb);
  gemm2_kernel<<<dim3(CAP_ / 256, D_ / 256, E_), 512, 0, stream>>>(hb, w2t, b2, tok_list, counts, prob, out);
  passthrough_kernel<<<N_, 256, 0, stream>>>(x, prob, slot, out);
}